// Round 1
// baseline (65.512 us; speedup 1.0000x reference)
//
#include <hip/hip_runtime.h>

#define Bx 16
#define Cx 64
#define Lx 512
#define Dx 768
#define NPx 68   // int((512+16)/8 + 2)
#define PER 7

// ---------------- Kernel A: m[b,l] = mean_c(x) / sqrt(var_c(x, ddof=1)) ----
__global__ void mean_var_kernel(const float* __restrict__ x,
                                float* __restrict__ m) {
    int idx = blockIdx.x * blockDim.x + threadIdx.x;  // b*Lx + l
    if (idx >= Bx * Lx) return;
    int b = idx / Lx, l = idx - b * Lx;
    const float* xp = x + (size_t)b * Cx * Lx + l;
    float s = 0.f, ss = 0.f;
#pragma unroll 8
    for (int c = 0; c < Cx; ++c) {
        float v = xp[(size_t)c * Lx];
        s += v;
        ss += v * v;
    }
    float mean = s / (float)Cx;
    float var = (ss - s * s / (float)Cx) / (float)(Cx - 1);
    m[idx] = mean * rsqrtf(var);
}

// ---------------- Kernel B: per-(b,c) decompose + projections + broadcast --
__global__ __launch_bounds__(256) void token_kernel(
    const float* __restrict__ x, const float* __restrict__ gamma,
    const float* __restrict__ beta, const float* __restrict__ m,
    const float* __restrict__ w_t, const float* __restrict__ b_t,
    const float* __restrict__ w_s, const float* __restrict__ b_s,
    const float* __restrict__ w_r, const float* __restrict__ b_r,
    const float* __restrict__ w_g, const float* __restrict__ b_g,
    float* __restrict__ out) {
    __shared__ float s_xt[Lx];
    __shared__ float s_tr[Lx];
    __shared__ float s_se[Lx];
    __shared__ float s_res[Lx];
    __shared__ float s_ph[PER];
    __shared__ float s_cat[48];
    __shared__ float s_p[Dx];

    const int bc = blockIdx.x;  // b*Cx + c
    const int b = bc / Cx;
    const int tid = threadIdx.x;

    const float* xp = x + (size_t)bc * Lx;
    const float* gp = gamma + (size_t)bc * Lx;
    const float* bp = beta + (size_t)bc * Lx;
    const float* mp = m + (size_t)b * Lx;

    // 1. xt = gamma*(x - m) + beta
    for (int l = tid; l < Lx; l += 256)
        s_xt[l] = gp[l] * (xp[l] - mp[l]) + bp[l];
    __syncthreads();

    // 2. trend = centered 7-pt MA, zero at edges (l in [3, Lx-4] valid)
    for (int l = tid; l < Lx; l += 256) {
        float t = 0.f;
        if (l >= 3 && l <= Lx - 4) {
#pragma unroll
            for (int k = -3; k <= 3; ++k) t += s_xt[l + k];
            t *= (1.f / 7.f);
        }
        s_tr[l] = t;
    }
    __syncthreads();

    // 3. per-phase averages of detrended interior
    if (tid < PER) {
        int p = tid;
        int l0 = p + 7 * ((3 - p + 6) / 7);  // smallest l>=3 with l%7==p
        float sum = 0.f;
        int cnt = 0;
        for (int l = l0; l <= Lx - 4; l += 7) {
            sum += s_xt[l] - s_tr[l];
            ++cnt;
        }
        s_ph[p] = sum / (float)cnt;
    }
    __syncthreads();
    if (tid == 0) {
        float mn = 0.f;
#pragma unroll
        for (int p = 0; p < PER; ++p) mn += s_ph[p];
        mn *= (1.f / 7.f);
#pragma unroll
        for (int p = 0; p < PER; ++p) s_ph[p] -= mn;
    }
    __syncthreads();

    // 4. seasonal (all l) + resid (interior only)
    for (int l = tid; l < Lx; l += 256) {
        float se = s_ph[l % PER];
        s_se[l] = se;
        s_res[l] = (l >= 3 && l <= Lx - 4) ? (s_xt[l] - s_tr[l] - se) : 0.f;
    }
    __syncthreads();

    // 5. cat[48] = [trend@w_t.T+b_t, seasonal@w_s.T+b_s, resid@w_r.T+b_r]
    {
        int j = tid >> 2, q = tid & 3;  // 4 lanes per output, 48 outputs
        if (j < 48) {
            const float* stream;
            const float* w;
            const float* bias;
            int jj;
            if (j < 16) {
                stream = s_tr; w = w_t; bias = b_t; jj = j;
            } else if (j < 32) {
                stream = s_se; w = w_s; bias = b_s; jj = j - 16;
            } else {
                stream = s_res; w = w_r; bias = b_r; jj = j - 32;
            }
            const float* wr = w + (size_t)jj * Lx + q * 128;
            const float* sp = stream + q * 128;
            float acc = 0.f;
#pragma unroll 4
            for (int i = 0; i < 128; ++i) acc += sp[i] * wr[i];
            acc += __shfl_xor(acc, 1);
            acc += __shfl_xor(acc, 2);
            if (q == 0) s_cat[j] = acc + bias[jj];
        }
    }
    __syncthreads();

    // 6. p[768] = cat @ w_g.T + b_g
    for (int d = tid; d < Dx; d += 256) {
        const float4* wg4 = reinterpret_cast<const float4*>(w_g + (size_t)d * 48);
        const float4* c4 = reinterpret_cast<const float4*>(s_cat);
        float acc = 0.f;
#pragma unroll
        for (int kk = 0; kk < 12; ++kk) {
            float4 w4 = wg4[kk], cc = c4[kk];
            acc += w4.x * cc.x + w4.y * cc.y + w4.z * cc.z + w4.w * cc.w;
        }
        s_p[d] = acc + b_g[d];
    }
    __syncthreads();

    // 7. broadcast p across NPx patch slots, coalesced float4 stores
    float4* outp = reinterpret_cast<float4*>(out + (size_t)bc * NPx * Dx);
    const float4* p4 = reinterpret_cast<const float4*>(s_p);
    const int nvec = NPx * (Dx / 4);  // 68*192 = 13056
    for (int i = tid; i < nvec; i += 256) {
        outp[i] = p4[i % 192];
    }
}

extern "C" void kernel_launch(void* const* d_in, const int* in_sizes, int n_in,
                              void* d_out, int out_size, void* d_ws,
                              size_t ws_size, hipStream_t stream) {
    const float* data_x = (const float*)d_in[0];
    // d_in[1] = data_y (unused by the reference)
    const float* gamma = (const float*)d_in[2];
    const float* beta = (const float*)d_in[3];
    const float* w_t = (const float*)d_in[4];
    const float* b_t = (const float*)d_in[5];
    const float* w_s = (const float*)d_in[6];
    const float* b_s = (const float*)d_in[7];
    const float* w_r = (const float*)d_in[8];
    const float* b_r = (const float*)d_in[9];
    const float* w_g = (const float*)d_in[10];
    const float* b_g = (const float*)d_in[11];
    float* out = (float*)d_out;
    float* m = (float*)d_ws;  // B*L floats = 32 KB

    int nthreads_m = Bx * Lx;
    mean_var_kernel<<<(nthreads_m + 255) / 256, 256, 0, stream>>>(data_x, m);

    token_kernel<<<Bx * Cx, 256, 0, stream>>>(data_x, gamma, beta, m, w_t, b_t,
                                              w_s, b_s, w_r, b_r, w_g, b_g,
                                              out);
}